// Round 1
// baseline (114.403 us; speedup 1.0000x reference)
//
#include <hip/hip_runtime.h>

// EmbeddingWithDropout: out[b,s,:] = weight[x[b,s],:] * ((u[x[b,s]] >= 0.1) ? 1/0.9 : 0)
// x: [64,2048] int32, weight: [100000,128] fp32, u: [100000] fp32
// out: [64,2048,128] fp32
//
// Memory-bound gather. One float4 per thread: 32 lanes per row (128 floats),
// each wave covers 2 rows. Coalesced 16B/lane loads + stores.

#define DIM 128
#define VEC_PER_ROW (DIM / 4)   // 32 float4 per row

__global__ __launch_bounds__(256) void embed_dropout_kernel(
    const int* __restrict__ x,
    const float* __restrict__ weight,
    const float* __restrict__ u,
    float4* __restrict__ out,
    int n_tokens)
{
    int gid = blockIdx.x * blockDim.x + threadIdx.x;   // one float4 per thread
    int token = gid >> 5;                              // /32
    int off   = gid & 31;
    if (token >= n_tokens) return;

    int idx = x[token];
    // per-row keep mask, scaled by 1/(1-dropout)
    float keep = (u[idx] >= 0.1f) ? (1.0f / 0.9f) : 0.0f;

    const float4* wrow = reinterpret_cast<const float4*>(weight)
                         + (size_t)idx * VEC_PER_ROW + off;
    float4 v = *wrow;
    v.x *= keep; v.y *= keep; v.z *= keep; v.w *= keep;
    out[gid] = v;
}

extern "C" void kernel_launch(void* const* d_in, const int* in_sizes, int n_in,
                              void* d_out, int out_size, void* d_ws, size_t ws_size,
                              hipStream_t stream) {
    const int*   x      = (const int*)d_in[0];     // [64*2048]
    const float* weight = (const float*)d_in[1];   // [100000*128]
    const float* u      = (const float*)d_in[2];   // [100000]
    float4*      out    = (float4*)d_out;

    int n_tokens = in_sizes[0];                    // 131072
    int n_vec4   = n_tokens * VEC_PER_ROW;         // total float4 elements
    int block = 256;
    int grid  = (n_vec4 + block - 1) / block;      // 16384

    embed_dropout_kernel<<<grid, block, 0, stream>>>(x, weight, u, out, n_tokens);
}